// Round 6
// baseline (296.118 us; speedup 1.0000x reference)
//
#include <hip/hip_runtime.h>
#include <stdint.h>

#define B_ 128
#define N_ 512
#define I_ 256
#define M_ 32
#define D_ 16

typedef __attribute__((ext_vector_type(4))) float f32x4;
typedef __attribute__((ext_vector_type(4))) float float4v;
typedef __attribute__((ext_vector_type(8))) short short8;     // 8 bf16 MFMA frag
typedef __attribute__((ext_vector_type(4))) unsigned int u32x4;
typedef __attribute__((ext_vector_type(4))) unsigned short ushort4v;

__device__ __forceinline__ float bf2f(unsigned short u) {
    union { unsigned int i; float f; } v; v.i = ((unsigned int)u) << 16; return v.f;
}
__device__ __forceinline__ unsigned short f2bf(float f) {
    union { float f; unsigned int i; } v; v.f = f;
    unsigned int r = v.i + 0x7FFFu + ((v.i >> 16) & 1u);   // RNE
    return (unsigned short)(r >> 16);
}

__device__ __forceinline__ short8 cvt8(float4v lo, float4v hi) {
    unsigned int u0, u1, u2, u3;
    asm("v_cvt_pk_bf16_f32 %0, %1, %2" : "=v"(u0) : "v"(lo[0]), "v"(lo[1]));
    asm("v_cvt_pk_bf16_f32 %0, %1, %2" : "=v"(u1) : "v"(lo[2]), "v"(lo[3]));
    asm("v_cvt_pk_bf16_f32 %0, %1, %2" : "=v"(u2) : "v"(hi[0]), "v"(hi[1]));
    asm("v_cvt_pk_bf16_f32 %0, %1, %2" : "=v"(u3) : "v"(hi[2]), "v"(hi[3]));
    u32x4 uv = {u0, u1, u2, u3};
    return __builtin_bit_cast(short8, uv);
}

// -----------------------------------------------------------------------------
// Kernel 0: x[b][n][i] fp32 -> xT[n][b][i] bf16.  Pure streaming.
// -----------------------------------------------------------------------------
__global__ __launch_bounds__(256) void conv_x(const float* __restrict__ x,
                                              unsigned short* __restrict__ xT) {
    const int rid = blockIdx.x * 4 + (threadIdx.x >> 6);   // rid = b*512 + n
    const int i0  = (threadIdx.x & 63) * 4;
    const int b   = rid >> 9;
    const int n   = rid & 511;
    float4v v = *(const float4v*)(x + (size_t)rid * I_ + i0);
    ushort4v h;
    h[0] = f2bf(v[0]); h[1] = f2bf(v[1]); h[2] = f2bf(v[2]); h[3] = f2bf(v[3]);
    *(ushort4v*)(xT + ((size_t)(n * B_ + b)) * I_ + i0) = h;
}

// -----------------------------------------------------------------------------
// Kernel 1: inputs_hat[b,m,n,d] = sum_i x[b,n,i] * W[m,n,d,i]
// One WAVE per (m,n) task: no LDS, no barriers. B-frags loaded straight from
// W (fp32 -> cvt_pk bf16 in regs, W read exactly once globally); A-frags from
// L2-resident bf16 xT. 8 row-tiles x 8 K-steps of MFMA 16x16x32, rolling
// register prefetch. XCD-chunked task order: each XCD owns a contiguous
// n-range so its xT slabs stay in its private L2.
// -----------------------------------------------------------------------------
__global__ __launch_bounds__(64) void hat_gemm(const float* __restrict__ W,
                                               const unsigned short* __restrict__ xT,
                                               unsigned short* __restrict__ hat) {
    // task swizzle: 16384 tasks (t = n*32 + m), 2048 contiguous per XCD
    const int L   = blockIdx.x;
    const int t   = (L & 7) * 2048 + (L >> 3);
    const int n   = t >> 5;
    const int m   = t & 31;

    const int lane = threadIdx.x;       // 0..63
    const int l15  = lane & 15;
    const int kq   = lane >> 4;         // 0..3; k = kq*8 + j within K-step

    // A: lane reads rows (a*16 + l15) of xT[n], 16B per K-step
    const unsigned short* abase = xT + ((size_t)n * B_ + l15) * I_ + kq * 8;
    // B: lane reads d-row l15 of W[m][n], 32B fp32 per K-step
    const float* wbase = W + (((size_t)m * N_ + n) * D_ + l15) * I_ + kq * 8;

    f32x4 acc[8];
    #pragma unroll
    for (int a = 0; a < 8; ++a) { f32x4 z = {0.f, 0.f, 0.f, 0.f}; acc[a] = z; }

    short8 acur[8], anxt[8];
    float4v blo, bhi, nlo, nhi;

    // preload K-step 0
    #pragma unroll
    for (int a = 0; a < 8; ++a)
        acur[a] = *(const short8*)(abase + (size_t)a * 16 * I_);
    blo = *(const float4v*)(wbase);
    bhi = *(const float4v*)(wbase + 4);

    #pragma unroll
    for (int ks = 0; ks < 8; ++ks) {
        // issue next K-step's loads (covered by this step's MFMAs)
        if (ks < 7) {
            #pragma unroll
            for (int a = 0; a < 8; ++a)
                anxt[a] = *(const short8*)(abase + (size_t)a * 16 * I_ + (ks + 1) * 32);
            nlo = *(const float4v*)(wbase + (ks + 1) * 32);
            nhi = *(const float4v*)(wbase + (ks + 1) * 32 + 4);
        }
        short8 bb = cvt8(blo, bhi);
        #pragma unroll
        for (int a = 0; a < 8; ++a)
            acc[a] = __builtin_amdgcn_mfma_f32_16x16x32_bf16(acur[a], bb, acc[a], 0, 0, 0);
        if (ks < 7) {
            #pragma unroll
            for (int a = 0; a < 8; ++a) acur[a] = anxt[a];
            blo = nlo; bhi = nhi;
        }
    }

    // epilogue: D map col(d) = lane&15, row = (lane>>4)*4 + r  (verified)
    #pragma unroll
    for (int a = 0; a < 8; ++a) {
        #pragma unroll
        for (int r = 0; r < 4; ++r) {
            const int brow = a * 16 + kq * 4 + r;
            const size_t idx = (((size_t)brow * M_ + m) * N_ + n) * D_ + l15;
            hat[idx] = f2bf(acc[a][r]);
        }
    }
}

// -----------------------------------------------------------------------------
// Kernel 2: dynamic routing (3 iterations), one block per batch element b.
// (unchanged — known-correct)
// -----------------------------------------------------------------------------
__global__ __launch_bounds__(512) void routing(const unsigned short* __restrict__ hat,
                                               float* __restrict__ out) {
    __shared__ float blog[M_][N_];
    __shared__ float cmax[N_];
    __shared__ float rcsum[N_];

    const int b    = blockIdx.x;
    const int tid  = threadIdx.x;
    const int lane = tid & 63;
    const int w    = tid >> 6;

    #pragma unroll
    for (int m = 0; m < M_; ++m) blog[m][tid] = 0.f;
    __syncthreads();

    float ov[4][16];

    for (int it = 0; it < 3; ++it) {
        {
            float mx = -3.4e38f;
            #pragma unroll
            for (int m = 0; m < M_; ++m) mx = fmaxf(mx, blog[m][tid]);
            float s = 0.f;
            #pragma unroll
            for (int m = 0; m < M_; ++m) s += __expf(blog[m][tid] - mx);
            cmax[tid]  = mx;
            rcsum[tid] = 1.f / s;
        }
        __syncthreads();

        float sacc[4][16];
        #pragma unroll
        for (int q = 0; q < 4; ++q)
            #pragma unroll
            for (int dd = 0; dd < 16; ++dd) sacc[q][dd] = 0.f;

        for (int r = 0; r < 8; ++r) {
            const int nn = r * 64 + lane;
            #pragma unroll
            for (int q = 0; q < 4; ++q) {
                const int m = w * 4 + q;
                const float cm = __expf(blog[m][nn] - cmax[nn]) * rcsum[nn];
                const size_t base = (((size_t)b * M_ + m) * N_ + nn) * D_;
                short8 h0 = *(const short8*)(hat + base);
                short8 h1 = *(const short8*)(hat + base + 8);
                #pragma unroll
                for (int dd = 0; dd < 8; ++dd) {
                    sacc[q][dd]     += cm * bf2f((unsigned short)h0[dd]);
                    sacc[q][8 + dd] += cm * bf2f((unsigned short)h1[dd]);
                }
            }
        }
        #pragma unroll
        for (int off = 32; off >= 1; off >>= 1) {
            #pragma unroll
            for (int q = 0; q < 4; ++q)
                #pragma unroll
                for (int dd = 0; dd < 16; ++dd)
                    sacc[q][dd] += __shfl_xor(sacc[q][dd], off, 64);
        }
        #pragma unroll
        for (int q = 0; q < 4; ++q) {
            float s2 = 0.f;
            #pragma unroll
            for (int dd = 0; dd < 16; ++dd) s2 += sacc[q][dd] * sacc[q][dd];
            const float scale = s2 / (1.f + s2) / sqrtf(s2 + 1e-7f);
            #pragma unroll
            for (int dd = 0; dd < 16; ++dd) ov[q][dd] = scale * sacc[q][dd];
        }

        if (it < 2) {
            for (int r = 0; r < 8; ++r) {
                const int nn = r * 64 + lane;
                #pragma unroll
                for (int q = 0; q < 4; ++q) {
                    const int m = w * 4 + q;
                    const size_t base = (((size_t)b * M_ + m) * N_ + nn) * D_;
                    short8 h0 = *(const short8*)(hat + base);
                    short8 h1 = *(const short8*)(hat + base + 8);
                    float dot = 0.f;
                    #pragma unroll
                    for (int dd = 0; dd < 8; ++dd) {
                        dot += ov[q][dd]     * bf2f((unsigned short)h0[dd]);
                        dot += ov[q][8 + dd] * bf2f((unsigned short)h1[dd]);
                    }
                    blog[m][nn] += dot;
                }
            }
        }
        __syncthreads();
    }

    if (lane == 0) {
        #pragma unroll
        for (int q = 0; q < 4; ++q) {
            const int m = w * 4 + q;
            #pragma unroll
            for (int c4 = 0; c4 < 4; ++c4) {
                float4v v;
                v[0] = ov[q][c4 * 4 + 0];
                v[1] = ov[q][c4 * 4 + 1];
                v[2] = ov[q][c4 * 4 + 2];
                v[3] = ov[q][c4 * 4 + 3];
                *(float4v*)&out[((size_t)b * M_ + m) * D_ + c4 * 4] = v;
            }
        }
    }
}

extern "C" void kernel_launch(void* const* d_in, const int* in_sizes, int n_in,
                              void* d_out, int out_size, void* d_ws, size_t ws_size,
                              hipStream_t stream) {
    const float* x = (const float*)d_in[0];        // [128, 512, 256] fp32
    const float* W = (const float*)d_in[1];        // [32, 512, 16, 256] fp32
    unsigned short* hat = (unsigned short*)d_ws;   // bf16 [128,32,512,16] = 64 MB
    unsigned short* xT  = (unsigned short*)((char*)d_ws + (size_t)64 * 1024 * 1024); // bf16 [512,128,256] = 32 MB
    float* out = (float*)d_out;                    // fp32 [128,32,16]

    conv_x<<<dim3((B_ * N_) / 4), dim3(256), 0, stream>>>(x, xT);
    hat_gemm<<<dim3(M_ * N_), dim3(64), 0, stream>>>(W, xT, hat);
    routing<<<dim3(B_), dim3(512), 0, stream>>>(hat, out);
}

// Round 7
// 187.089 us; speedup vs baseline: 1.5828x; 1.5828x over previous
//
#include <hip/hip_runtime.h>
#include <stdint.h>

#define B_ 128
#define N_ 512
#define I_ 256
#define M_ 32
#define D_ 16

typedef __attribute__((ext_vector_type(4))) float f32x4;
typedef __attribute__((ext_vector_type(4))) float float4v;
typedef __attribute__((ext_vector_type(8))) short short8;     // 8 bf16 MFMA frag
typedef __attribute__((ext_vector_type(4))) unsigned short ushort4v;

__device__ __forceinline__ float bf2f(unsigned short u) {
    union { unsigned int i; float f; } v; v.i = ((unsigned int)u) << 16; return v.f;
}
__device__ __forceinline__ unsigned short f2bf(float f) {
    union { float f; unsigned int i; } v; v.f = f;
    unsigned int r = v.i + 0x7FFFu + ((v.i >> 16) & 1u);   // RNE
    return (unsigned short)(r >> 16);
}

// -----------------------------------------------------------------------------
// Kernel 1: inputs_hat[b,m,n,d] = sum_i x[b,n,i] * W[m,n,d,i]
// r3 structure (best measured), C-tile shrunk 128x128 -> 128x64:
//   LDS 36.8 -> 27.6 KB (5 blocks/CU vs 4), grid 2048 -> 4096 blocks.
// Staging: 16 lanes x 256B contiguous per row; reg-prefetch next k-tile.
// XCD-chunked block order: each XCD owns a contiguous n-range.
// -----------------------------------------------------------------------------
#define LDK 72   // 64 + 8 pad (ushort)

__global__ __launch_bounds__(256) void hat_gemm(const float* __restrict__ x,
                                                const float* __restrict__ W,
                                                unsigned short* __restrict__ hat) {
    __shared__ unsigned short As[128][LDK];   // [b_local][k]      18.4 KB
    __shared__ unsigned short Bs[64][LDK];    // [col=m_l*16+d][k]  9.2 KB

    // block decode: 4096 blocks; XCD (L&7) gets contiguous n in [xcd*64, +64)
    const int L   = blockIdx.x;
    const int xcd = L & 7;
    const int i   = L >> 3;             // 0..511
    const int n   = xcd * 64 + (i >> 3);
    const int mc  = i & 7;              // m in [mc*4, mc*4+4)

    const int tid  = threadIdx.x;
    const int lane = tid & 63;
    const int w    = tid >> 6;          // wave 0..3 -> b-rows [w*32, w*32+32)
    const int l15  = lane & 15;

    // staging: sgrp-th lane-group handles rows {sgrp, 16+sgrp, ...}; 16 lanes
    // cover one row's 256B (64 fp32) contiguous.
    const int sgrp  = tid >> 4;         // 0..15
    const int klane = (tid & 15) * 4;   // fp32 k-offset within 64

    const float* xrow = x + ((size_t)sgrp * N_ + n) * I_ + klane;                    // +r*16 rows
    const float* wrow = W + (((size_t)(mc * 4) * N_ + n) * D_ + sgrp) * I_ + klane;  // +r m's
    const size_t xstep = (size_t)16 * N_ * I_;
    const size_t wstep = (size_t)N_ * D_ * I_;

    float4v pa[8], pb[4];

    f32x4 acc[2][4];
    #pragma unroll
    for (int a = 0; a < 2; ++a)
        #pragma unroll
        for (int c = 0; c < 4; ++c) { f32x4 z = {0.f, 0.f, 0.f, 0.f}; acc[a][c] = z; }

    // prologue: k-tile 0 loads
    #pragma unroll
    for (int r = 0; r < 8; ++r) pa[r] = *(const float4v*)(xrow + (size_t)r * xstep);
    #pragma unroll
    for (int r = 0; r < 4; ++r) pb[r] = *(const float4v*)(wrow + (size_t)r * wstep);

    for (int kt = 0; kt < 4; ++kt) {
        // convert + LDS write
        #pragma unroll
        for (int r = 0; r < 8; ++r) {
            ushort4v h;
            h[0] = f2bf(pa[r][0]); h[1] = f2bf(pa[r][1]);
            h[2] = f2bf(pa[r][2]); h[3] = f2bf(pa[r][3]);
            *(ushort4v*)&As[r * 16 + sgrp][klane] = h;
        }
        #pragma unroll
        for (int r = 0; r < 4; ++r) {
            ushort4v h;
            h[0] = f2bf(pb[r][0]); h[1] = f2bf(pb[r][1]);
            h[2] = f2bf(pb[r][2]); h[3] = f2bf(pb[r][3]);
            *(ushort4v*)&Bs[r * 16 + sgrp][klane] = h;
        }
        __syncthreads();

        // prefetch k-tile kt+1 (in flight across MFMA)
        if (kt < 3) {
            const int k0 = (kt + 1) * 64;
            #pragma unroll
            for (int r = 0; r < 8; ++r)
                pa[r] = *(const float4v*)(xrow + (size_t)r * xstep + k0);
            #pragma unroll
            for (int r = 0; r < 4; ++r)
                pb[r] = *(const float4v*)(wrow + (size_t)r * wstep + k0);
        }

        // MFMA on staged BK=64 (two K=32 steps)
        #pragma unroll
        for (int ks = 0; ks < 2; ++ks) {
            const int kb = ks * 32 + ((lane >> 4) << 3);
            short8 a0 = *(const short8*)&As[w * 32 +      l15][kb];
            short8 a1 = *(const short8*)&As[w * 32 + 16 + l15][kb];
            #pragma unroll
            for (int ct = 0; ct < 4; ++ct) {
                short8 bb = *(const short8*)&Bs[ct * 16 + l15][kb];
                acc[0][ct] = __builtin_amdgcn_mfma_f32_16x16x32_bf16(a0, bb, acc[0][ct], 0, 0, 0);
                acc[1][ct] = __builtin_amdgcn_mfma_f32_16x16x32_bf16(a1, bb, acc[1][ct], 0, 0, 0);
            }
        }
        __syncthreads();
    }

    // epilogue: D map col = lane&15, row = (lane>>4)*4 + r (verified)
    const int d  = l15;
    const int rq = lane >> 4;
    #pragma unroll
    for (int rt = 0; rt < 2; ++rt) {
        #pragma unroll
        for (int ct = 0; ct < 4; ++ct) {
            const int m = mc * 4 + ct;
            #pragma unroll
            for (int r = 0; r < 4; ++r) {
                const int brow = w * 32 + rt * 16 + rq * 4 + r;
                const size_t idx = (((size_t)brow * M_ + m) * N_ + n) * D_ + d;
                hat[idx] = f2bf(acc[rt][ct][r]);
            }
        }
    }
}

// -----------------------------------------------------------------------------
// Kernel 2: dynamic routing (3 iterations), one block per batch element b.
// (unchanged — known-correct)
// -----------------------------------------------------------------------------
__global__ __launch_bounds__(512) void routing(const unsigned short* __restrict__ hat,
                                               float* __restrict__ out) {
    __shared__ float blog[M_][N_];
    __shared__ float cmax[N_];
    __shared__ float rcsum[N_];

    const int b    = blockIdx.x;
    const int tid  = threadIdx.x;
    const int lane = tid & 63;
    const int w    = tid >> 6;

    #pragma unroll
    for (int m = 0; m < M_; ++m) blog[m][tid] = 0.f;
    __syncthreads();

    float ov[4][16];

    for (int it = 0; it < 3; ++it) {
        {
            float mx = -3.4e38f;
            #pragma unroll
            for (int m = 0; m < M_; ++m) mx = fmaxf(mx, blog[m][tid]);
            float s = 0.f;
            #pragma unroll
            for (int m = 0; m < M_; ++m) s += __expf(blog[m][tid] - mx);
            cmax[tid]  = mx;
            rcsum[tid] = 1.f / s;
        }
        __syncthreads();

        float sacc[4][16];
        #pragma unroll
        for (int q = 0; q < 4; ++q)
            #pragma unroll
            for (int dd = 0; dd < 16; ++dd) sacc[q][dd] = 0.f;

        for (int r = 0; r < 8; ++r) {
            const int nn = r * 64 + lane;
            #pragma unroll
            for (int q = 0; q < 4; ++q) {
                const int m = w * 4 + q;
                const float cm = __expf(blog[m][nn] - cmax[nn]) * rcsum[nn];
                const size_t base = (((size_t)b * M_ + m) * N_ + nn) * D_;
                short8 h0 = *(const short8*)(hat + base);
                short8 h1 = *(const short8*)(hat + base + 8);
                #pragma unroll
                for (int dd = 0; dd < 8; ++dd) {
                    sacc[q][dd]     += cm * bf2f((unsigned short)h0[dd]);
                    sacc[q][8 + dd] += cm * bf2f((unsigned short)h1[dd]);
                }
            }
        }
        #pragma unroll
        for (int off = 32; off >= 1; off >>= 1) {
            #pragma unroll
            for (int q = 0; q < 4; ++q)
                #pragma unroll
                for (int dd = 0; dd < 16; ++dd)
                    sacc[q][dd] += __shfl_xor(sacc[q][dd], off, 64);
        }
        #pragma unroll
        for (int q = 0; q < 4; ++q) {
            float s2 = 0.f;
            #pragma unroll
            for (int dd = 0; dd < 16; ++dd) s2 += sacc[q][dd] * sacc[q][dd];
            const float scale = s2 / (1.f + s2) / sqrtf(s2 + 1e-7f);
            #pragma unroll
            for (int dd = 0; dd < 16; ++dd) ov[q][dd] = scale * sacc[q][dd];
        }

        if (it < 2) {
            for (int r = 0; r < 8; ++r) {
                const int nn = r * 64 + lane;
                #pragma unroll
                for (int q = 0; q < 4; ++q) {
                    const int m = w * 4 + q;
                    const size_t base = (((size_t)b * M_ + m) * N_ + nn) * D_;
                    short8 h0 = *(const short8*)(hat + base);
                    short8 h1 = *(const short8*)(hat + base + 8);
                    float dot = 0.f;
                    #pragma unroll
                    for (int dd = 0; dd < 8; ++dd) {
                        dot += ov[q][dd]     * bf2f((unsigned short)h0[dd]);
                        dot += ov[q][8 + dd] * bf2f((unsigned short)h1[dd]);
                    }
                    blog[m][nn] += dot;
                }
            }
        }
        __syncthreads();
    }

    if (lane == 0) {
        #pragma unroll
        for (int q = 0; q < 4; ++q) {
            const int m = w * 4 + q;
            #pragma unroll
            for (int c4 = 0; c4 < 4; ++c4) {
                float4v v;
                v[0] = ov[q][c4 * 4 + 0];
                v[1] = ov[q][c4 * 4 + 1];
                v[2] = ov[q][c4 * 4 + 2];
                v[3] = ov[q][c4 * 4 + 3];
                *(float4v*)&out[((size_t)b * M_ + m) * D_ + c4 * 4] = v;
            }
        }
    }
}

extern "C" void kernel_launch(void* const* d_in, const int* in_sizes, int n_in,
                              void* d_out, int out_size, void* d_ws, size_t ws_size,
                              hipStream_t stream) {
    const float* x = (const float*)d_in[0];        // [128, 512, 256] fp32
    const float* W = (const float*)d_in[1];        // [32, 512, 16, 256] fp32
    unsigned short* hat = (unsigned short*)d_ws;   // bf16 [128,32,512,16] = 64 MB
    float* out = (float*)d_out;                    // fp32 [128,32,16]

    hat_gemm<<<dim3(4096), dim3(256), 0, stream>>>(x, W, hat);
    routing<<<dim3(B_), dim3(512), 0, stream>>>(hat, out);
}

// Round 8
// 183.720 us; speedup vs baseline: 1.6118x; 1.0183x over previous
//
#include <hip/hip_runtime.h>
#include <stdint.h>

#define B_ 128
#define N_ 512
#define I_ 256
#define M_ 32
#define D_ 16

typedef __attribute__((ext_vector_type(4))) float f32x4;
typedef __attribute__((ext_vector_type(4))) float float4v;
typedef __attribute__((ext_vector_type(8))) short short8;     // 8 bf16 MFMA frag
typedef __attribute__((ext_vector_type(4))) unsigned short ushort4v;

__device__ __forceinline__ float bf2f(unsigned short u) {
    union { unsigned int i; float f; } v; v.i = ((unsigned int)u) << 16; return v.f;
}
__device__ __forceinline__ unsigned short f2bf(float f) {
    union { float f; unsigned int i; } v; v.f = f;
    unsigned int r = v.i + 0x7FFFu + ((v.i >> 16) & 1u);   // RNE
    return (unsigned short)(r >> 16);
}

// -----------------------------------------------------------------------------
// Kernel 1: inputs_hat[b,m,n,d] = sum_i x[b,n,i] * W[m,n,d,i]
// r7 structure, ONE change: __launch_bounds__(256, 4) -> VGPR cap 128 so the
// 12-float4 k-tile prefetch (48 VGPRs) stays register-resident instead of
// being serialized by the allocator's default low-VGPR target (r7: VGPR=60,
// loads serialized at ~900ns each = the measured 47us block lifetime).
// -----------------------------------------------------------------------------
#define LDK 72   // 64 + 8 pad (ushort)

__global__ __launch_bounds__(256, 4) void hat_gemm(const float* __restrict__ x,
                                                   const float* __restrict__ W,
                                                   unsigned short* __restrict__ hat) {
    __shared__ unsigned short As[128][LDK];   // [b_local][k]      18.4 KB
    __shared__ unsigned short Bs[64][LDK];    // [col=m_l*16+d][k]  9.2 KB

    // block decode: 4096 blocks; XCD (L&7) gets contiguous n in [xcd*64, +64)
    const int L   = blockIdx.x;
    const int xcd = L & 7;
    const int i   = L >> 3;             // 0..511
    const int n   = xcd * 64 + (i >> 3);
    const int mc  = i & 7;              // m in [mc*4, mc*4+4)

    const int tid  = threadIdx.x;
    const int lane = tid & 63;
    const int w    = tid >> 6;          // wave 0..3 -> b-rows [w*32, w*32+32)
    const int l15  = lane & 15;

    // staging: 16 lanes cover one row's 256B (64 fp32) contiguous.
    const int sgrp  = tid >> 4;         // 0..15
    const int klane = (tid & 15) * 4;   // fp32 k-offset within 64

    const float* xrow = x + ((size_t)sgrp * N_ + n) * I_ + klane;                    // +r*16 rows
    const float* wrow = W + (((size_t)(mc * 4) * N_ + n) * D_ + sgrp) * I_ + klane;  // +r m's
    const size_t xstep = (size_t)16 * N_ * I_;
    const size_t wstep = (size_t)N_ * D_ * I_;

    float4v pa[8], pb[4];

    f32x4 acc[2][4];
    #pragma unroll
    for (int a = 0; a < 2; ++a)
        #pragma unroll
        for (int c = 0; c < 4; ++c) { f32x4 z = {0.f, 0.f, 0.f, 0.f}; acc[a][c] = z; }

    // prologue: k-tile 0 loads
    #pragma unroll
    for (int r = 0; r < 8; ++r) pa[r] = *(const float4v*)(xrow + (size_t)r * xstep);
    #pragma unroll
    for (int r = 0; r < 4; ++r) pb[r] = *(const float4v*)(wrow + (size_t)r * wstep);

    for (int kt = 0; kt < 4; ++kt) {
        // convert + LDS write
        #pragma unroll
        for (int r = 0; r < 8; ++r) {
            ushort4v h;
            h[0] = f2bf(pa[r][0]); h[1] = f2bf(pa[r][1]);
            h[2] = f2bf(pa[r][2]); h[3] = f2bf(pa[r][3]);
            *(ushort4v*)&As[r * 16 + sgrp][klane] = h;
        }
        #pragma unroll
        for (int r = 0; r < 4; ++r) {
            ushort4v h;
            h[0] = f2bf(pb[r][0]); h[1] = f2bf(pb[r][1]);
            h[2] = f2bf(pb[r][2]); h[3] = f2bf(pb[r][3]);
            *(ushort4v*)&Bs[r * 16 + sgrp][klane] = h;
        }
        __syncthreads();

        // prefetch k-tile kt+1 (12 independent loads, in flight across MFMA;
        // first use is after the next barrier)
        if (kt < 3) {
            const int k0 = (kt + 1) * 64;
            #pragma unroll
            for (int r = 0; r < 8; ++r)
                pa[r] = *(const float4v*)(xrow + (size_t)r * xstep + k0);
            #pragma unroll
            for (int r = 0; r < 4; ++r)
                pb[r] = *(const float4v*)(wrow + (size_t)r * wstep + k0);
        }

        // MFMA on staged BK=64 (two K=32 steps)
        #pragma unroll
        for (int ks = 0; ks < 2; ++ks) {
            const int kb = ks * 32 + ((lane >> 4) << 3);
            short8 a0 = *(const short8*)&As[w * 32 +      l15][kb];
            short8 a1 = *(const short8*)&As[w * 32 + 16 + l15][kb];
            #pragma unroll
            for (int ct = 0; ct < 4; ++ct) {
                short8 bb = *(const short8*)&Bs[ct * 16 + l15][kb];
                acc[0][ct] = __builtin_amdgcn_mfma_f32_16x16x32_bf16(a0, bb, acc[0][ct], 0, 0, 0);
                acc[1][ct] = __builtin_amdgcn_mfma_f32_16x16x32_bf16(a1, bb, acc[1][ct], 0, 0, 0);
            }
        }
        __syncthreads();
    }

    // epilogue: D map col = lane&15, row = (lane>>4)*4 + r (verified)
    const int d  = l15;
    const int rq = lane >> 4;
    #pragma unroll
    for (int rt = 0; rt < 2; ++rt) {
        #pragma unroll
        for (int ct = 0; ct < 4; ++ct) {
            const int m = mc * 4 + ct;
            #pragma unroll
            for (int r = 0; r < 4; ++r) {
                const int brow = w * 32 + rt * 16 + rq * 4 + r;
                const size_t idx = (((size_t)brow * M_ + m) * N_ + n) * D_ + d;
                hat[idx] = f2bf(acc[rt][ct][r]);
            }
        }
    }
}

// -----------------------------------------------------------------------------
// Kernel 2: dynamic routing (3 iterations), one block per batch element b.
// (unchanged — known-correct)
// -----------------------------------------------------------------------------
__global__ __launch_bounds__(512) void routing(const unsigned short* __restrict__ hat,
                                               float* __restrict__ out) {
    __shared__ float blog[M_][N_];
    __shared__ float cmax[N_];
    __shared__ float rcsum[N_];

    const int b    = blockIdx.x;
    const int tid  = threadIdx.x;
    const int lane = tid & 63;
    const int w    = tid >> 6;

    #pragma unroll
    for (int m = 0; m < M_; ++m) blog[m][tid] = 0.f;
    __syncthreads();

    float ov[4][16];

    for (int it = 0; it < 3; ++it) {
        {
            float mx = -3.4e38f;
            #pragma unroll
            for (int m = 0; m < M_; ++m) mx = fmaxf(mx, blog[m][tid]);
            float s = 0.f;
            #pragma unroll
            for (int m = 0; m < M_; ++m) s += __expf(blog[m][tid] - mx);
            cmax[tid]  = mx;
            rcsum[tid] = 1.f / s;
        }
        __syncthreads();

        float sacc[4][16];
        #pragma unroll
        for (int q = 0; q < 4; ++q)
            #pragma unroll
            for (int dd = 0; dd < 16; ++dd) sacc[q][dd] = 0.f;

        for (int r = 0; r < 8; ++r) {
            const int nn = r * 64 + lane;
            #pragma unroll
            for (int q = 0; q < 4; ++q) {
                const int m = w * 4 + q;
                const float cm = __expf(blog[m][nn] - cmax[nn]) * rcsum[nn];
                const size_t base = (((size_t)b * M_ + m) * N_ + nn) * D_;
                short8 h0 = *(const short8*)(hat + base);
                short8 h1 = *(const short8*)(hat + base + 8);
                #pragma unroll
                for (int dd = 0; dd < 8; ++dd) {
                    sacc[q][dd]     += cm * bf2f((unsigned short)h0[dd]);
                    sacc[q][8 + dd] += cm * bf2f((unsigned short)h1[dd]);
                }
            }
        }
        #pragma unroll
        for (int off = 32; off >= 1; off >>= 1) {
            #pragma unroll
            for (int q = 0; q < 4; ++q)
                #pragma unroll
                for (int dd = 0; dd < 16; ++dd)
                    sacc[q][dd] += __shfl_xor(sacc[q][dd], off, 64);
        }
        #pragma unroll
        for (int q = 0; q < 4; ++q) {
            float s2 = 0.f;
            #pragma unroll
            for (int dd = 0; dd < 16; ++dd) s2 += sacc[q][dd] * sacc[q][dd];
            const float scale = s2 / (1.f + s2) / sqrtf(s2 + 1e-7f);
            #pragma unroll
            for (int dd = 0; dd < 16; ++dd) ov[q][dd] = scale * sacc[q][dd];
        }

        if (it < 2) {
            for (int r = 0; r < 8; ++r) {
                const int nn = r * 64 + lane;
                #pragma unroll
                for (int q = 0; q < 4; ++q) {
                    const int m = w * 4 + q;
                    const size_t base = (((size_t)b * M_ + m) * N_ + nn) * D_;
                    short8 h0 = *(const short8*)(hat + base);
                    short8 h1 = *(const short8*)(hat + base + 8);
                    float dot = 0.f;
                    #pragma unroll
                    for (int dd = 0; dd < 8; ++dd) {
                        dot += ov[q][dd]     * bf2f((unsigned short)h0[dd]);
                        dot += ov[q][8 + dd] * bf2f((unsigned short)h1[dd]);
                    }
                    blog[m][nn] += dot;
                }
            }
        }
        __syncthreads();
    }

    if (lane == 0) {
        #pragma unroll
        for (int q = 0; q < 4; ++q) {
            const int m = w * 4 + q;
            #pragma unroll
            for (int c4 = 0; c4 < 4; ++c4) {
                float4v v;
                v[0] = ov[q][c4 * 4 + 0];
                v[1] = ov[q][c4 * 4 + 1];
                v[2] = ov[q][c4 * 4 + 2];
                v[3] = ov[q][c4 * 4 + 3];
                *(float4v*)&out[((size_t)b * M_ + m) * D_ + c4 * 4] = v;
            }
        }
    }
}

extern "C" void kernel_launch(void* const* d_in, const int* in_sizes, int n_in,
                              void* d_out, int out_size, void* d_ws, size_t ws_size,
                              hipStream_t stream) {
    const float* x = (const float*)d_in[0];        // [128, 512, 256] fp32
    const float* W = (const float*)d_in[1];        // [32, 512, 16, 256] fp32
    unsigned short* hat = (unsigned short*)d_ws;   // bf16 [128,32,512,16] = 64 MB
    float* out = (float*)d_out;                    // fp32 [128,32,16]

    hat_gemm<<<dim3(4096), dim3(256), 0, stream>>>(x, W, hat);
    routing<<<dim3(B_), dim3(512), 0, stream>>>(hat, out);
}